// Round 7
// baseline (665.139 us; speedup 1.0000x reference)
//
#include <hip/hip_runtime.h>
#include <stdint.h>

namespace {

constexpr int Bn = 1024;  // batch
constexpr int Tn = 1024;  // timesteps
constexpr int Hn = 50;    // hidden
constexpr int Pn = 16;    // params per (b,t)
constexpr int KP = 25;    // h pairs (H=50 -> 25 half2)

typedef _Float16 h2 __attribute__((ext_vector_type(2)));

__device__ __forceinline__ float fast_rcp(float x) { return __builtin_amdgcn_rcpf(x); }
__device__ __forceinline__ float fast_sigmoid(float x) {
    return fast_rcp(1.0f + __expf(-x));
}
__device__ __forceinline__ float fast_tanh(float x) {
    return 1.0f - 2.0f * fast_rcp(__expf(2.0f * x) + 1.0f);
}
__device__ __forceinline__ float fdot2(h2 a, h2 b, float c) {
    return __builtin_amdgcn_fdot2(a, b, c, false);  // v_dot2_f32_f16, fp32 acc
}
__device__ __forceinline__ h2 pkfma(h2 a, h2 b, h2 c) {
    return __builtin_elementwise_fma(a, b, c);      // v_pk_fma_f16
}

// ---------------------------------------------------------------------------
// r6 post-mortem: single wave/SIMD issues ~1 VALU instr per 4.2cy (measured
// across r3/r5/r6, instruction-type independent) -> cadence-bound. Need 2
// waves/SIMD to saturate the SIMD-32 pipe (2cy/wave64 op). This kernel: 2
// waves per batch element, k-split over h pairs (wave0: pairs 0..12, wave1:
// pairs 13..24 + x/bias base). Partial gate sums exchanged through a 4KB LDS
// ping-pong, ONE __syncthreads per step; activations/c/h duplicated in both
// waves (bit-identical) so h stays lane-local for readlane broadcast. Each
// wave readlanes and hbuf-stores only its own pair range.
// ---------------------------------------------------------------------------
template<int K0, int NK, bool HASX>
__device__ __forceinline__ void run_tloop(
    h2 (&w0)[NK], h2 (&w1)[NK], h2 (&w2)[NK], h2 (&w3)[NK],
    float wih0, float wih1, float wih2, float wih3,
    float bb0, float bb1, float bb2, float bb3,
    const float4* __restrict__ xb4, uint32_t* __restrict__ hb, bool writer,
    float4 (&part)[2][2][64], int wid, int lane)
{
    const h2 one2  = h2{(_Float16)1.0f, (_Float16)1.0f};
    const h2 zero2 = h2{(_Float16)0.0f, (_Float16)0.0f};

    float h = 0.0f, c = 0.0f;
    int sp[NK];
    #pragma unroll
    for (int k = 0; k < NK; ++k) sp[k] = 0;

    float4 xA = make_float4(0.f, 0.f, 0.f, 0.f);
    if constexpr (HASX) xA = xb4[0];

    for (int tt = 0; tt < Tn / 4; ++tt) {
        float4 xB = make_float4(0.f, 0.f, 0.f, 0.f);
        if constexpr (HASX) {
            if (tt + 1 < Tn / 4) xB = xb4[tt + 1];
        }
        const float xs[4] = {xA.x, xA.y, xA.z, xA.w};

        #pragma unroll
        for (int u = 0; u < 4; ++u) {
            // partial matvec over this wave's k-range: NK*4 v_pk_fma_f16,
            // 4 independent chains (one per gate)
            h2 a0 = zero2, a1 = zero2, a2 = zero2, a3 = zero2;
            #pragma unroll
            for (int k = 0; k < NK; ++k) {
                const h2 hp = __builtin_bit_cast(h2, sp[k]);
                a0 = pkfma(hp, w0[k], a0);
                a1 = pkfma(hp, w1[k], a1);
                a2 = pkfma(hp, w2[k], a2);
                a3 = pkfma(hp, w3[k], a3);
            }
            float s0, s1, s2, s3;
            if constexpr (HASX) {
                s0 = fdot2(a0, one2, fmaf(xs[u], wih0, bb0));
                s1 = fdot2(a1, one2, fmaf(xs[u], wih1, bb1));
                s2 = fdot2(a2, one2, fmaf(xs[u], wih2, bb2));
                s3 = fdot2(a3, one2, fmaf(xs[u], wih3, bb3));
            } else {
                s0 = fdot2(a0, one2, 0.0f);
                s1 = fdot2(a1, one2, 0.0f);
                s2 = fdot2(a2, one2, 0.0f);
                s3 = fdot2(a3, one2, 0.0f);
            }

            // exchange partials with partner wave (ping-pong parity = u&1,
            // one barrier/step; write->bar->read ordering is hazard-free)
            part[u & 1][wid][lane] = make_float4(s0, s1, s2, s3);
            __syncthreads();
            const float4 p = part[u & 1][wid ^ 1][lane];
            s0 += p.x; s1 += p.y; s2 += p.z; s3 += p.w;

            // activations + state (duplicated both waves, bit-identical)
            const float ig = fast_sigmoid(s0);
            const float fg = fast_sigmoid(s1);
            const float gg = fast_tanh(s2);
            const float og = fast_sigmoid(s3);
            c = fmaf(fg, c, ig * gg);
            h = og * fast_tanh(c);

            // pack (h_j, h_{j^1}): DPP quad-perm [1,0,3,2] + cvt_pkrtz
            const int hi = __builtin_bit_cast(int, h);
            const int hj = __builtin_amdgcn_update_dpp(0, hi, 0xB1, 0xF, 0xF, true);
            const int packed = __builtin_bit_cast(int,
                __builtin_amdgcn_cvt_pkrtz(h, __builtin_bit_cast(float, hj)));

            // deferred projection: this wave's pairs only
            if (writer) hb[tt * 4 + u] = (uint32_t)packed;

            // broadcast this wave's k-range for next step
            #pragma unroll
            for (int k = 0; k < NK; ++k)
                sp[k] = __builtin_amdgcn_readlane(packed, 2 * (K0 + k));
        }
        xA = xB;
    }
}

__global__ __attribute__((amdgpu_flat_work_group_size(128, 128), amdgpu_waves_per_eu(2, 2)))
void lstm_core_h2(const float* __restrict__ x, const float* __restrict__ W_ih,
                  const float* __restrict__ W_hh, const float* __restrict__ b_ih,
                  const float* __restrict__ b_hh, uint32_t* __restrict__ hbuf)
{
    __shared__ float4 part[2][2][64];  // [parity][wave][lane] = 4 KB

    const int tid  = threadIdx.x;
    const int lane = tid & 63;
    const int wid  = __builtin_amdgcn_readfirstlane(tid >> 6);  // 0 or 1
    const int b    = blockIdx.x;
    const int jj   = (lane < Hn) ? lane : Hn - 1;

    const float4* xb4 = (const float4*)(x + (size_t)b * Tn);
    // hbuf [b][pair][t]; each wave's even lanes in its pair range store
    uint32_t* hb = hbuf + ((size_t)b * KP + (size_t)(lane >> 1)) * Tn;

    const float* r0 = W_hh + (size_t)(0 * Hn + jj) * Hn;
    const float* r1 = W_hh + (size_t)(1 * Hn + jj) * Hn;
    const float* r2 = W_hh + (size_t)(2 * Hn + jj) * Hn;
    const float* r3 = W_hh + (size_t)(3 * Hn + jj) * Hn;

    if (wid == 0) {
        constexpr int K0 = 0, NK = 13;
        h2 w0[NK], w1[NK], w2[NK], w3[NK];
        #pragma unroll
        for (int k = 0; k < NK; ++k) {
            const int g = 2 * (K0 + k);
            w0[k] = h2{(_Float16)r0[g], (_Float16)r0[g + 1]};
            w1[k] = h2{(_Float16)r1[g], (_Float16)r1[g + 1]};
            w2[k] = h2{(_Float16)r2[g], (_Float16)r2[g + 1]};
            w3[k] = h2{(_Float16)r3[g], (_Float16)r3[g + 1]};
        }
        #pragma unroll
        for (int k = 0; k < NK; ++k)
            asm volatile("" : "+v"(w0[k]), "+v"(w1[k]), "+v"(w2[k]), "+v"(w3[k]));

        const bool writer = ((lane & 1) == 0) && ((lane >> 1) < K0 + NK);
        run_tloop<K0, NK, false>(w0, w1, w2, w3,
                                 0.f, 0.f, 0.f, 0.f, 0.f, 0.f, 0.f, 0.f,
                                 xb4, hb, writer, part, wid, lane);
    } else {
        constexpr int K0 = 13, NK = 12;
        h2 w0[NK], w1[NK], w2[NK], w3[NK];
        #pragma unroll
        for (int k = 0; k < NK; ++k) {
            const int g = 2 * (K0 + k);
            w0[k] = h2{(_Float16)r0[g], (_Float16)r0[g + 1]};
            w1[k] = h2{(_Float16)r1[g], (_Float16)r1[g + 1]};
            w2[k] = h2{(_Float16)r2[g], (_Float16)r2[g + 1]};
            w3[k] = h2{(_Float16)r3[g], (_Float16)r3[g + 1]};
        }
        #pragma unroll
        for (int k = 0; k < NK; ++k)
            asm volatile("" : "+v"(w0[k]), "+v"(w1[k]), "+v"(w2[k]), "+v"(w3[k]));

        const float wih0 = W_ih[0 * Hn + jj];
        const float wih1 = W_ih[1 * Hn + jj];
        const float wih2 = W_ih[2 * Hn + jj];
        const float wih3 = W_ih[3 * Hn + jj];
        const float bb0 = b_ih[0 * Hn + jj] + b_hh[0 * Hn + jj];
        const float bb1 = b_ih[1 * Hn + jj] + b_hh[1 * Hn + jj];
        const float bb2 = b_ih[2 * Hn + jj] + b_hh[2 * Hn + jj];
        const float bb3 = b_ih[3 * Hn + jj] + b_hh[3 * Hn + jj];

        const bool writer = ((lane & 1) == 0) && ((lane >> 1) >= K0) &&
                            ((lane >> 1) < K0 + NK);
        run_tloop<K0, NK, true>(w0, w1, w2, w3,
                                wih0, wih1, wih2, wih3, bb0, bb1, bb2, bb3,
                                xb4, hb, writer, part, wid, lane);
    }
}

// ---------------------------------------------------------------------------
// Post-kernel: out[b,t] = h(b,t).Wlin[0:50] + params(b,t).Wlin[50:66] + b_lin.
// One thread per (b,t); hbuf [b][k][t] -> lane-coalesced dword loads.
// ---------------------------------------------------------------------------
__global__ __launch_bounds__(256)
void post_proj(const uint32_t* __restrict__ hbuf, const float* __restrict__ params,
               const float* __restrict__ W_lin, const float* __restrict__ b_lin,
               float* __restrict__ out)
{
    const int i = blockIdx.x * 256 + threadIdx.x;  // 0 .. B*T-1 (exact grid)
    const int b = i >> 10;                         // Tn = 1024
    const int t = i & (Tn - 1);

    float s = b_lin[0];
    const uint32_t* hp = hbuf + (size_t)b * KP * Tn + t;
    #pragma unroll
    for (int k = 0; k < KP; ++k) {
        const h2 wlk = h2{(_Float16)W_lin[2 * k], (_Float16)W_lin[2 * k + 1]};
        s = fdot2(__builtin_bit_cast(h2, hp[(size_t)k * Tn]), wlk, s);
    }

    const float4* p4 = (const float4*)(params + (size_t)i * Pn);
    const float4 a = p4[0], bq = p4[1], cq = p4[2], dq = p4[3];
    const float* wp = W_lin + Hn;
    s += a.x  * wp[ 0] + a.y  * wp[ 1] + a.z  * wp[ 2] + a.w  * wp[ 3];
    s += bq.x * wp[ 4] + bq.y * wp[ 5] + bq.z * wp[ 6] + bq.w * wp[ 7];
    s += cq.x * wp[ 8] + cq.y * wp[ 9] + cq.z * wp[10] + cq.w * wp[11];
    s += dq.x * wp[12] + dq.y * wp[13] + dq.z * wp[14] + dq.w * wp[15];
    out[i] = s;
}

// ---------------------------------------------------------------------------
// FALLBACK (ws too small for hbuf): round-3 fused kernels, proven correct.
// ---------------------------------------------------------------------------
__global__ __launch_bounds__(256)
void params_proj(const float* __restrict__ params, const float* __restrict__ W_lin,
                 float* __restrict__ pp)
{
    const int i = blockIdx.x * 256 + threadIdx.x;
    const float4* p4 = (const float4*)(params + (size_t)i * Pn);
    const float4 a = p4[0], b = p4[1], c = p4[2], d = p4[3];
    const float* wl = W_lin + Hn;
    float s;
    s  = a.x * wl[ 0] + a.y * wl[ 1] + a.z * wl[ 2] + a.w * wl[ 3];
    s += b.x * wl[ 4] + b.y * wl[ 5] + b.z * wl[ 6] + b.w * wl[ 7];
    s += c.x * wl[ 8] + c.y * wl[ 9] + c.z * wl[10] + c.w * wl[11];
    s += d.x * wl[12] + d.y * wl[13] + d.z * wl[14] + d.w * wl[15];
    pp[i] = s;
}

__global__ __attribute__((amdgpu_flat_work_group_size(64, 64), amdgpu_waves_per_eu(1, 1)))
void lstm_core_fused(const float* __restrict__ x, const float* __restrict__ W_ih,
                     const float* __restrict__ W_hh, const float* __restrict__ b_ih,
                     const float* __restrict__ b_hh, const float* __restrict__ W_lin,
                     const float* __restrict__ b_lin, const float* __restrict__ pp,
                     float* __restrict__ out)
{
    const int b    = blockIdx.x;
    const int lane = threadIdx.x;
    const int jj   = (lane < Hn) ? lane : Hn - 1;

    h2 w0[KP], w1[KP], w2[KP], w3[KP], wl[KP];
    const float* r0 = W_hh + (size_t)(0 * Hn + jj) * Hn;
    const float* r1 = W_hh + (size_t)(1 * Hn + jj) * Hn;
    const float* r2 = W_hh + (size_t)(2 * Hn + jj) * Hn;
    const float* r3 = W_hh + (size_t)(3 * Hn + jj) * Hn;
    #pragma unroll
    for (int k = 0; k < KP; ++k) {
        w0[k] = h2{(_Float16)r0[2 * k], (_Float16)r0[2 * k + 1]};
        w1[k] = h2{(_Float16)r1[2 * k], (_Float16)r1[2 * k + 1]};
        w2[k] = h2{(_Float16)r2[2 * k], (_Float16)r2[2 * k + 1]};
        w3[k] = h2{(_Float16)r3[2 * k], (_Float16)r3[2 * k + 1]};
        wl[k] = h2{(_Float16)W_lin[2 * k], (_Float16)W_lin[2 * k + 1]};
    }
    #pragma unroll
    for (int k = 0; k < KP; ++k) {
        asm volatile("" : "+v"(w0[k]), "+v"(w1[k]), "+v"(w2[k]), "+v"(w3[k]), "+v"(wl[k]));
    }

    const float wih0 = W_ih[0 * Hn + jj];
    const float wih1 = W_ih[1 * Hn + jj];
    const float wih2 = W_ih[2 * Hn + jj];
    const float wih3 = W_ih[3 * Hn + jj];
    const float bb0 = b_ih[0 * Hn + jj] + b_hh[0 * Hn + jj];
    const float bb1 = b_ih[1 * Hn + jj] + b_hh[1 * Hn + jj];
    const float bb2 = b_ih[2 * Hn + jj] + b_hh[2 * Hn + jj];
    const float bb3 = b_ih[3 * Hn + jj] + b_hh[3 * Hn + jj];
    const float blin = b_lin[0];

    const float4* xb4 = (const float4*)(x + (size_t)b * Tn);
    const float4* pp4 = (const float4*)(pp + (size_t)b * Tn);
    float4* ob4 = (float4*)(out + (size_t)b * Tn);

    float h = 0.0f, c = 0.0f;
    int sp[KP];
    #pragma unroll
    for (int k = 0; k < KP; ++k) sp[k] = 0;

    float4 xA = xb4[0], pA = pp4[0];

    for (int tt = 0; tt < Tn / 4; ++tt) {
        float4 xB = make_float4(0.f, 0.f, 0.f, 0.f), pB = xB;
        if (tt + 1 < Tn / 4) { xB = xb4[tt + 1]; pB = pp4[tt + 1]; }

        const float xs[4] = {xA.x, xA.y, xA.z, xA.w};
        const float ps[4] = {pA.x, pA.y, pA.z, pA.w};
        float o4[4];

        #pragma unroll
        for (int u = 0; u < 4; ++u) {
            float a0 = fmaf(xs[u], wih0, bb0);
            float a1 = fmaf(xs[u], wih1, bb1);
            float a2 = fmaf(xs[u], wih2, bb2);
            float a3 = fmaf(xs[u], wih3, bb3);
            #pragma unroll
            for (int k = 0; k < KP; ++k) {
                const h2 hp = __builtin_bit_cast(h2, sp[k]);
                a0 = fdot2(hp, w0[k], a0);
                a1 = fdot2(hp, w1[k], a1);
                a2 = fdot2(hp, w2[k], a2);
                a3 = fdot2(hp, w3[k], a3);
            }

            const float ig = fast_sigmoid(a0);
            const float fg = fast_sigmoid(a1);
            const float gg = fast_tanh(a2);
            const float og = fast_sigmoid(a3);
            c = fmaf(fg, c, ig * gg);
            h = og * fast_tanh(c);

            const int hi = __builtin_bit_cast(int, h);
            const int hj = __builtin_amdgcn_update_dpp(0, hi, 0xB1, 0xF, 0xF, true);
            const int packed = __builtin_bit_cast(int,
                __builtin_amdgcn_cvt_pkrtz(h, __builtin_bit_cast(float, hj)));

            #pragma unroll
            for (int k = 0; k < KP; ++k)
                sp[k] = __builtin_amdgcn_readlane(packed, 2 * k);

            float prj = ps[u] + blin;
            #pragma unroll
            for (int k = 0; k < KP; ++k)
                prj = fdot2(__builtin_bit_cast(h2, sp[k]), wl[k], prj);
            o4[u] = prj;
        }

        if (lane == 0) ob4[tt] = make_float4(o4[0], o4[1], o4[2], o4[3]);
        xA = xB; pA = pB;
    }
}

} // namespace

extern "C" void kernel_launch(void* const* d_in, const int* in_sizes, int n_in,
                              void* d_out, int out_size, void* d_ws, size_t ws_size,
                              hipStream_t stream) {
    const float* x      = (const float*)d_in[0];
    const float* params = (const float*)d_in[1];
    const float* W_ih   = (const float*)d_in[2];
    const float* W_hh   = (const float*)d_in[3];
    const float* b_ih   = (const float*)d_in[4];
    const float* b_hh   = (const float*)d_in[5];
    const float* W_lin  = (const float*)d_in[6];
    const float* b_lin  = (const float*)d_in[7];
    float* out = (float*)d_out;

    const size_t hbuf_bytes = (size_t)Bn * KP * Tn * sizeof(uint32_t);  // 100 MB

    if (ws_size >= hbuf_bytes) {
        uint32_t* hbuf = (uint32_t*)d_ws;
        lstm_core_h2<<<dim3(Bn), dim3(128), 0, stream>>>(
            x, W_ih, W_hh, b_ih, b_hh, hbuf);
        post_proj<<<dim3(Bn * Tn / 256), dim3(256), 0, stream>>>(
            hbuf, params, W_lin, b_lin, out);
    } else {
        float* pp = (float*)d_ws;  // 4 MB
        params_proj<<<dim3(Bn * Tn / 256), dim3(256), 0, stream>>>(params, W_lin, pp);
        lstm_core_fused<<<dim3(Bn), dim3(64), 0, stream>>>(
            x, W_ih, W_hh, b_ih, b_hh, W_lin, b_lin, pp, out);
    }
}